// Round 9
// baseline (384.151 us; speedup 1.0000x reference)
//
#include <hip/hip_runtime.h>

#define NN 4096     // nodes
#define HC 8        // heads
#define DC 32       // dim per head
#define OC 256      // out channels = HC*DC
#define KC 256      // in channels
#define CF 6        // curvature features

typedef __bf16 bf16_t;
typedef bf16_t bf16x8 __attribute__((ext_vector_type(8)));
typedef float f32x4 __attribute__((ext_vector_type(4)));
typedef float f32x2 __attribute__((ext_vector_type(2)));
typedef unsigned u32x4 __attribute__((ext_vector_type(4)));

#if defined(__has_builtin)
#if __has_builtin(__builtin_amdgcn_exp2f)
#define EXP2F(x) __builtin_amdgcn_exp2f(x)
#else
#define EXP2F(x) exp2f(x)
#endif
#else
#define EXP2F(x) exp2f(x)
#endif

// bf16 pair (one dword: lo16 = t_even, hi16 = t_odd) -> f32x2 (bf16 is
// truncated f32: unpack = 1 shl + 1 and).
static __device__ __forceinline__ f32x2 unpk(unsigned dw) {
  union { unsigned u; float f; } lo, hi;
  lo.u = dw << 16;
  hi.u = dw & 0xffff0000u;
  return (f32x2){lo.f, hi.f};
}

// ---------------------------------------------------------------------------
// Kernel 1: heterogeneous prep.
// Blocks 0..511 (gemm role): h-GEMM (64 rows x 1 head) + e_l (f32) +
//   e_r packed bf16 in attn's lane order (erP[c][q][h][t8]) + V as bf16 in
//   attn's B-fragment order (hT2[head][c][q][d32][t8]).
// Blocks 512..2559 (pack role): ballot-pack adj -> 2MB bitmask; cfT (f32,
//   i-side) + cfP packed bf16 in attn's lane order (cfP[c][q][f][t8]); Wc2.
// ---------------------------------------------------------------------------
__global__ __launch_bounds__(256) void prep_all(const float* __restrict__ x,
                                                const float* __restrict__ W,
                                                const float* __restrict__ a_l,
                                                const float* __restrict__ a_r,
                                                const int* __restrict__ adj,
                                                const float* __restrict__ cfeat,
                                                const float* __restrict__ Wc,
                                                const float* __restrict__ gate,
                                                float* __restrict__ e_l2,
                                                bf16_t* __restrict__ erP,
                                                bf16_t* __restrict__ hT2,
                                                unsigned* __restrict__ adjb,
                                                float* __restrict__ cfT,
                                                bf16_t* __restrict__ cfP,
                                                float* __restrict__ Wc2) {
  __shared__ float As[16][68];   // [k][i]
  __shared__ float Bs[16][36];   // [k][c]
  __shared__ float Ct[DC][65];   // [c][i]
  const float LOG2E = 1.44269504088896340736f;
  const int t = threadIdx.x;
  const int bid = blockIdx.x;

  if (bid >= 512) {
    // ---------------- pack role ----------------
    const int pb = bid - 512;                    // 0..2047
    const int ptid = pb * 256 + t;
    const int lane = t & 63;
    const int wv = pb * 4 + (t >> 6);            // 0..8191
    for (int it = 0; it < 32; ++it) {
      int g = wv * 32 + it;                      // segment id
      int i = g >> 6;
      int s = g & 63;
      int v = adj[(size_t)i * NN + s * 64 + lane];
      unsigned long long m = __ballot(v > 0);
      if (lane == 0) *(unsigned long long*)(adjb + i * 128 + s * 2) = m;
    }
    if (ptid < NN * CF) {
      int j = ptid / CF, f = ptid - j * CF;
      float v = cfeat[ptid];
      cfT[f * NN + j] = v;
      int cc = j >> 5, qq = (j >> 3) & 3, tt = j & 7;
      cfP[((cc * 4 + qq) * CF + f) * 8 + tt] = (bf16_t)v;
    }
    if (ptid < HC * CF) Wc2[ptid] = Wc[ptid] * gate[0] * LOG2E;
    return;
  }

  // ---------------- gemm role ----------------
  const int i0 = (bid & 63) * 64;
  const int head = bid >> 6;
  const int c0 = head * DC;
  const int tx = t & 7;          // col group (4 cols)
  const int ty = t >> 3;         // row pair (2 rows)
  const int lr = t >> 2;         // staging row 0..63
  const int lk = (t & 3) * 4;    // staging k 0,4,8,12

  float acc[2][4] = {};
  for (int kk = 0; kk < KC; kk += 16) {
    f32x4 av = *(const f32x4*)&x[(size_t)(i0 + lr) * KC + kk + lk];
    f32x4 wv;
    if (t < 128) wv = *(const f32x4*)&W[(size_t)(c0 + (t >> 2)) * KC + kk + lk];
    __syncthreads();
    As[lk + 0][lr] = av[0]; As[lk + 1][lr] = av[1];
    As[lk + 2][lr] = av[2]; As[lk + 3][lr] = av[3];
    if (t < 128) {
      int br = t >> 2;
      Bs[lk + 0][br] = wv[0]; Bs[lk + 1][br] = wv[1];
      Bs[lk + 2][br] = wv[2]; Bs[lk + 3][br] = wv[3];
    }
    __syncthreads();
#pragma unroll
    for (int k = 0; k < 16; ++k) {
      f32x2 a = *(const f32x2*)&As[k][ty * 2];
      f32x4 b = *(const f32x4*)&Bs[k][tx * 4];
#pragma unroll
      for (int r = 0; r < 2; ++r)
#pragma unroll
        for (int u = 0; u < 4; ++u)
          acc[r][u] += a[r] * b[u];
    }
  }

  // e_l (f32) / e_r (packed bf16, attn lane order), reduce across 8 tx lanes
  f32x4 al4 = *(const f32x4*)&a_l[c0 + tx * 4];
  f32x4 ar4 = *(const f32x4*)&a_r[c0 + tx * 4];
#pragma unroll
  for (int r = 0; r < 2; ++r) {
    float el = acc[r][0] * al4[0] + acc[r][1] * al4[1] +
               acc[r][2] * al4[2] + acc[r][3] * al4[3];
    float er = acc[r][0] * ar4[0] + acc[r][1] * ar4[1] +
               acc[r][2] * ar4[2] + acc[r][3] * ar4[3];
    el += __shfl_xor(el, 1, 64); el += __shfl_xor(el, 2, 64); el += __shfl_xor(el, 4, 64);
    er += __shfl_xor(er, 1, 64); er += __shfl_xor(er, 2, 64); er += __shfl_xor(er, 4, 64);
    if (tx == 0) {
      int j = i0 + ty * 2 + r;
      e_l2[j * HC + head] = el * LOG2E;
      int cc = j >> 5, qq = (j >> 3) & 3, tt = j & 7;
      erP[((cc * 4 + qq) * HC + head) * 8 + tt] = (bf16_t)(er * LOG2E);
    }
  }

  // transpose to B-fragment layout via LDS
#pragma unroll
  for (int r = 0; r < 2; ++r)
#pragma unroll
    for (int u = 0; u < 4; ++u)
      Ct[tx * 4 + u][ty * 2 + r] = acc[r][u];
  __syncthreads();
  const size_t base = (size_t)head * (NN / 32) * 1024 + (size_t)(bid & 63) * 2048;
#pragma unroll
  for (int rep = 0; rep < 8; ++rep) {
    int idx = rep * 256 + t;                 // enumerates [chunkL][q][d][t8]
    int dd = (idx >> 3) & 31;
    int jl = (idx >> 10) * 32 + ((idx >> 8) & 3) * 8 + (idx & 7);
    hT2[base + idx] = (bf16_t)Ct[dd][jl];
  }
}

// ---------------------------------------------------------------------------
// Kernel 2: fused masked attention, 2 heads/block, register-prefetched.
// Grid (NN/16, 4) = 1024 blocks x 384 threads (6 waves), lb(384,6):
// 4 blocks/CU x 6 waves = 24 waves/CU, ALL 1024 blocks co-resident in one
// round (4x384=1536<=2048 thr; 6 waves/EU x 85-reg cap = 510<=512 regs;
// R8 measured 80 combined regs for this exact body -> fits).
// R8 at 16 waves/CU: dur/VALU-busy = 1.56 -> residual load-latency stall;
// this buys 1.5x TLP at zero register cost. j-chunks strided by 6
// (waves 0-1 do 22 subiters, 2-5 do 21; ~3% imbalance).
// cfP/erP/adjb prefetch one iteration ahead; V loads at body top.
// No online max (logits bounded, masked p == 0 exactly).
// ---------------------------------------------------------------------------
__global__ __launch_bounds__(384, 6) void attn(const unsigned* __restrict__ adjb,
                                               const float* __restrict__ e_l2,
                                               const float* __restrict__ cfT,
                                               const float* __restrict__ Wc2,
                                               const u32x4* __restrict__ cfP4,
                                               const u32x4* __restrict__ erP4,
                                               const bf16_t* __restrict__ hT2,
                                               float* __restrict__ out) {
  __shared__ float Obuf[16][64];
  __shared__ float Sbuf[16][2];
  const int tid = threadIdx.x;
  const int w = tid >> 6;        // 0..5
  const int lane = tid & 63;
  const int il = lane & 15;
  const int quad = lane >> 4;
  const int ibase = blockIdx.x * 16;
  const int hg = blockIdx.y;     // head pair: heads hg*2, hg*2+1
  const int i = ibase + il;

  for (int idx = tid; idx < 16 * 64; idx += 384) (&Obuf[0][0])[idx] = 0.f;
  if (tid < 32) (&Sbuf[0][0])[tid] = 0.f;
  __syncthreads();

  f32x2 cfi2[CF];
#pragma unroll
  for (int f = 0; f < CF; ++f) { float v = cfT[f * NN + i]; cfi2[f] = (f32x2){v, v}; }
  f32x2 el2[2];
  {
    f32x2 e0 = *(const f32x2*)&e_l2[i * HC + hg * 2];
#pragma unroll
    for (int u = 0; u < 2; ++u) el2[u] = (f32x2){e0[u], e0[u]};
  }
  float wc[2][CF];
#pragma unroll
  for (int h = 0; h < 2; ++h)
#pragma unroll
    for (int f = 0; f < CF; ++f) wc[h][f] = Wc2[(hg * 2 + h) * CF + f];

  f32x4 acc[2][2];
#pragma unroll
  for (int h = 0; h < 2; ++h)
#pragma unroll
    for (int d = 0; d < 2; ++d) acc[h][d] = (f32x4){0.f, 0.f, 0.f, 0.f};
  f32x2 S2[2];
#pragma unroll
  for (int h = 0; h < 2; ++h) S2[h] = (f32x2){0.f, 0.f};

  const bf16_t* hTbase = hT2 + (size_t)hg * 2 * ((NN / 32) * 1024) + quad * 256 + il * 8;
  const u32x4* cfb = cfP4 + quad * CF;           // c-stride 4*CF  (u32x4 units)
  const u32x4* erb = erP4 + quad * HC + hg * 2;  // c-stride 4*HC
  const unsigned* adjrow = adjb + i * 128;

  // ---- prime the prefetch registers for chunk c = w ----
  u32x4 cfc[CF];
#pragma unroll
  for (int f = 0; f < CF; ++f) cfc[f] = cfb[w * (4 * CF) + f];
  u32x4 erc[2];
#pragma unroll
  for (int h = 0; h < 2; ++h) erc[h] = erb[w * (4 * HC) + h];
  unsigned mc = adjrow[w];

  for (int c = w; c < NN / 32; c += 6) {
    // V fragments: issued at body top, consumed at the end (~500 cyc lead)
    const bf16_t* bp0 = hTbase + c * 1024;
    const bf16_t* bp1 = bp0 + (NN / 32) * 1024;
    bf16x8 b00 = *(const bf16x8*)bp0;
    bf16x8 b01 = *(const bf16x8*)(bp0 + 128);
    bf16x8 b10 = *(const bf16x8*)bp1;
    bf16x8 b11 = *(const bf16x8*)(bp1 + 128);

    // leaky(el + er) from prefetched erc (registers, no wait)
    f32x2 arg[2][4];
#pragma unroll
    for (int h = 0; h < 2; ++h)
#pragma unroll
      for (int p = 0; p < 4; ++p) {
        f32x2 s = el2[h] + unpk(erc[h][p]);
        arg[h][p] = __builtin_elementwise_max(s, 0.2f * s);
      }
    // curvature bias from prefetched cfc
#pragma unroll
    for (int f = 0; f < CF; ++f) {
#pragma unroll
      for (int p = 0; p < 4; ++p) {
        f32x2 d2 = cfi2[f] - unpk(cfc[f][p]);
        f32x2 ab = __builtin_elementwise_max(d2, -d2);
#pragma unroll
        for (int h = 0; h < 2; ++h) {
          f32x2 wsp = (f32x2){wc[h][f], wc[h][f]};
          arg[h][p] = __builtin_elementwise_fma(ab, wsp, arg[h][p]);
        }
      }
    }

    // ---- prefetch chunk c+6 (cur buffers dead; one full body of lead) ----
    const int cn = (c + 6) & (NN / 32 - 1);
    const unsigned m8 = (mc >> (quad * 8)) & 0xffu;
#pragma unroll
    for (int f = 0; f < CF; ++f) cfc[f] = cfb[cn * (4 * CF) + f];
#pragma unroll
    for (int h = 0; h < 2; ++h) erc[h] = erb[cn * (4 * HC) + h];
    mc = adjrow[cn];

    // mask bits -> float pairs
    f32x2 mf2[4];
#pragma unroll
    for (int p = 0; p < 4; ++p)
      mf2[p] = (f32x2){(float)((m8 >> (2 * p)) & 1u), (float)((m8 >> (2 * p + 1)) & 1u)};

#pragma unroll
    for (int h = 0; h < 2; ++h) {
      bf16x8 af;
#pragma unroll
      for (int p = 0; p < 4; ++p) {
        f32x2 pv = (f32x2){EXP2F(arg[h][p][0]), EXP2F(arg[h][p][1])};
        pv = pv * mf2[p];          // v_pk_mul
        S2[h] += pv;               // v_pk_add
        af[2 * p] = (bf16_t)pv[0];
        af[2 * p + 1] = (bf16_t)pv[1];
      }
      acc[h][0] = __builtin_amdgcn_mfma_f32_16x16x32_bf16(af, h ? b10 : b00, acc[h][0], 0, 0, 0);
      acc[h][1] = __builtin_amdgcn_mfma_f32_16x16x32_bf16(af, h ? b11 : b01, acc[h][1], 0, 0, 0);
    }
  }

  // reduce S across quads (lanes il, il+16, il+32, il+48)
#pragma unroll
  for (int h = 0; h < 2; ++h) {
    float v = S2[h][0] + S2[h][1];
    v += __shfl_xor(v, 16, 64);
    v += __shfl_xor(v, 32, 64);
    if (quad == 0) atomicAdd(&Sbuf[il][h], v);
  }
  // accumulate O partials: C/D layout row = quad*4+r (i), col = il (d half)
#pragma unroll
  for (int h = 0; h < 2; ++h)
#pragma unroll
    for (int dh = 0; dh < 2; ++dh)
#pragma unroll
      for (int r = 0; r < 4; ++r)
        atomicAdd(&Obuf[quad * 4 + r][h * DC + dh * 16 + il], acc[h][dh][r]);
  __syncthreads();

  // epilogue: divide by softmax denom, coalesced store
  for (int idx = tid; idx < 16 * 64; idx += 384) {
    int row = idx >> 6;
    int colg = idx & 63;
    out[(size_t)(ibase + row) * OC + hg * 64 + colg] =
        Obuf[row][colg] / Sbuf[row][colg >> 5];
  }
}

// ---------------------------------------------------------------------------
extern "C" void kernel_launch(void* const* d_in, const int* in_sizes, int n_in,
                              void* d_out, int out_size, void* d_ws, size_t ws_size,
                              hipStream_t stream) {
  const float* x    = (const float*)d_in[0];
  // d_in[1] = positions — unused by the reference
  const float* cfeat= (const float*)d_in[2];
  const int*   adj  = (const int*)d_in[3];
  const float* W    = (const float*)d_in[4];
  const float* a_l  = (const float*)d_in[5];
  const float* a_r  = (const float*)d_in[6];
  const float* Wc   = (const float*)d_in[7];
  const float* gate = (const float*)d_in[8];
  float* out = (float*)d_out;

  char* ws = (char*)d_ws;
  bf16_t*   hT2  = (bf16_t*)ws;                              // 2 MB
  unsigned* adjb = (unsigned*)(ws + (2u << 20));             // 2 MB
  float*    e_l2 = (float*)(ws + (4u << 20));                // 128 KB
  float*    cfT  = (float*)(ws + (4u << 20) + (128u << 10)); // 96 KB
  float*    Wc2  = (float*)(ws + (4u << 20) + (256u << 10)); // 192 B
  bf16_t*   cfP  = (bf16_t*)(ws + (4u << 20) + (320u << 10));// 48 KB
  bf16_t*   erP  = (bf16_t*)(ws + (4u << 20) + (384u << 10));// 64 KB

  prep_all<<<2560, 256, 0, stream>>>(x, W, a_l, a_r, adj, cfeat, Wc, gate,
                                     e_l2, erP, hT2, adjb, cfT, cfP, Wc2);
  attn<<<dim3(NN / 16, 4), 384, 0, stream>>>(adjb, e_l2, cfT, Wc2,
                                             (const u32x4*)cfP, (const u32x4*)erP,
                                             hT2, out);
}

// Round 10
// 318.110 us; speedup vs baseline: 1.2076x; 1.2076x over previous
//
#include <hip/hip_runtime.h>

#define NN 4096     // nodes
#define HC 8        // heads
#define DC 32       // dim per head
#define OC 256      // out channels = HC*DC
#define KC 256      // in channels
#define CF 6        // curvature features

typedef __bf16 bf16_t;
typedef bf16_t bf16x8 __attribute__((ext_vector_type(8)));
typedef float f32x4 __attribute__((ext_vector_type(4)));
typedef float f32x2 __attribute__((ext_vector_type(2)));
typedef unsigned u32x4 __attribute__((ext_vector_type(4)));

#if defined(__has_builtin)
#if __has_builtin(__builtin_amdgcn_exp2f)
#define EXP2F(x) __builtin_amdgcn_exp2f(x)
#else
#define EXP2F(x) exp2f(x)
#endif
#else
#define EXP2F(x) exp2f(x)
#endif

// bf16 pair (one dword: lo16 = t_even, hi16 = t_odd) -> f32x2 (bf16 is
// truncated f32: unpack = 1 shl + 1 and).
static __device__ __forceinline__ f32x2 unpk(unsigned dw) {
  union { unsigned u; float f; } lo, hi;
  lo.u = dw << 16;
  hi.u = dw & 0xffff0000u;
  return (f32x2){lo.f, hi.f};
}

// ---------------------------------------------------------------------------
// Kernel 1: heterogeneous prep.
// Blocks 0..511 (gemm role): h-GEMM (64 rows x 1 head) + e_l (f32) +
//   e_r packed bf16 in attn's lane order (erP[c][q][h][t8]) + V as bf16 in
//   attn's B-fragment order (hT2[head][c][q][d32][t8]).
// Blocks 512..2559 (pack role): ballot-pack adj -> 2MB bitmask; cfT (f32,
//   i-side) + cfP packed bf16 in attn's lane order (cfP[c][q][f][t8]); Wc2.
// ---------------------------------------------------------------------------
__global__ __launch_bounds__(256) void prep_all(const float* __restrict__ x,
                                                const float* __restrict__ W,
                                                const float* __restrict__ a_l,
                                                const float* __restrict__ a_r,
                                                const int* __restrict__ adj,
                                                const float* __restrict__ cfeat,
                                                const float* __restrict__ Wc,
                                                const float* __restrict__ gate,
                                                float* __restrict__ e_l2,
                                                bf16_t* __restrict__ erP,
                                                bf16_t* __restrict__ hT2,
                                                unsigned* __restrict__ adjb,
                                                float* __restrict__ cfT,
                                                bf16_t* __restrict__ cfP,
                                                float* __restrict__ Wc2) {
  __shared__ float As[16][68];   // [k][i]
  __shared__ float Bs[16][36];   // [k][c]
  __shared__ float Ct[DC][65];   // [c][i]
  const float LOG2E = 1.44269504088896340736f;
  const int t = threadIdx.x;
  const int bid = blockIdx.x;

  if (bid >= 512) {
    // ---------------- pack role ----------------
    const int pb = bid - 512;                    // 0..2047
    const int ptid = pb * 256 + t;
    const int lane = t & 63;
    const int wv = pb * 4 + (t >> 6);            // 0..8191
    for (int it = 0; it < 32; ++it) {
      int g = wv * 32 + it;                      // segment id
      int i = g >> 6;
      int s = g & 63;
      int v = adj[(size_t)i * NN + s * 64 + lane];
      unsigned long long m = __ballot(v > 0);
      if (lane == 0) *(unsigned long long*)(adjb + i * 128 + s * 2) = m;
    }
    if (ptid < NN * CF) {
      int j = ptid / CF, f = ptid - j * CF;
      float v = cfeat[ptid];
      cfT[f * NN + j] = v;
      int cc = j >> 5, qq = (j >> 3) & 3, tt = j & 7;
      cfP[((cc * 4 + qq) * CF + f) * 8 + tt] = (bf16_t)v;
    }
    if (ptid < HC * CF) Wc2[ptid] = Wc[ptid] * gate[0] * LOG2E;
    return;
  }

  // ---------------- gemm role ----------------
  const int i0 = (bid & 63) * 64;
  const int head = bid >> 6;
  const int c0 = head * DC;
  const int tx = t & 7;          // col group (4 cols)
  const int ty = t >> 3;         // row pair (2 rows)
  const int lr = t >> 2;         // staging row 0..63
  const int lk = (t & 3) * 4;    // staging k 0,4,8,12

  float acc[2][4] = {};
  for (int kk = 0; kk < KC; kk += 16) {
    f32x4 av = *(const f32x4*)&x[(size_t)(i0 + lr) * KC + kk + lk];
    f32x4 wv;
    if (t < 128) wv = *(const f32x4*)&W[(size_t)(c0 + (t >> 2)) * KC + kk + lk];
    __syncthreads();
    As[lk + 0][lr] = av[0]; As[lk + 1][lr] = av[1];
    As[lk + 2][lr] = av[2]; As[lk + 3][lr] = av[3];
    if (t < 128) {
      int br = t >> 2;
      Bs[lk + 0][br] = wv[0]; Bs[lk + 1][br] = wv[1];
      Bs[lk + 2][br] = wv[2]; Bs[lk + 3][br] = wv[3];
    }
    __syncthreads();
#pragma unroll
    for (int k = 0; k < 16; ++k) {
      f32x2 a = *(const f32x2*)&As[k][ty * 2];
      f32x4 b = *(const f32x4*)&Bs[k][tx * 4];
#pragma unroll
      for (int r = 0; r < 2; ++r)
#pragma unroll
        for (int u = 0; u < 4; ++u)
          acc[r][u] += a[r] * b[u];
    }
  }

  // e_l (f32) / e_r (packed bf16, attn lane order), reduce across 8 tx lanes
  f32x4 al4 = *(const f32x4*)&a_l[c0 + tx * 4];
  f32x4 ar4 = *(const f32x4*)&a_r[c0 + tx * 4];
#pragma unroll
  for (int r = 0; r < 2; ++r) {
    float el = acc[r][0] * al4[0] + acc[r][1] * al4[1] +
               acc[r][2] * al4[2] + acc[r][3] * al4[3];
    float er = acc[r][0] * ar4[0] + acc[r][1] * ar4[1] +
               acc[r][2] * ar4[2] + acc[r][3] * ar4[3];
    el += __shfl_xor(el, 1, 64); el += __shfl_xor(el, 2, 64); el += __shfl_xor(el, 4, 64);
    er += __shfl_xor(er, 1, 64); er += __shfl_xor(er, 2, 64); er += __shfl_xor(er, 4, 64);
    if (tx == 0) {
      int j = i0 + ty * 2 + r;
      e_l2[j * HC + head] = el * LOG2E;
      int cc = j >> 5, qq = (j >> 3) & 3, tt = j & 7;
      erP[((cc * 4 + qq) * HC + head) * 8 + tt] = (bf16_t)(er * LOG2E);
    }
  }

  // transpose to B-fragment layout via LDS
#pragma unroll
  for (int r = 0; r < 2; ++r)
#pragma unroll
    for (int u = 0; u < 4; ++u)
      Ct[tx * 4 + u][ty * 2 + r] = acc[r][u];
  __syncthreads();
  const size_t base = (size_t)head * (NN / 32) * 1024 + (size_t)(bid & 63) * 2048;
#pragma unroll
  for (int rep = 0; rep < 8; ++rep) {
    int idx = rep * 256 + t;                 // enumerates [chunkL][q][d][t8]
    int dd = (idx >> 3) & 31;
    int jl = (idx >> 10) * 32 + ((idx >> 8) & 3) * 8 + (idx & 7);
    hT2[base + idx] = (bf16_t)Ct[dd][jl];
  }
}

// ---------------------------------------------------------------------------
// Kernel 2: fused masked attention, 2 heads/block, register-prefetched.
// Grid (NN/16, 4) = 1024 blocks x 320 threads (5 waves), lb(320,5):
// 4 blocks/CU x 5 waves = 20 waves/CU, all 1024 blocks co-resident in one
// round. Register cap: floor(512/5)=102 -> granule 96, leaving 16 regs of
// slack over the measured 80 (64 VGPR + 16 AGPR) this body needs.
// LESSON (R2/R7/R9): a launch-bounds cap within one granule of the actual
// requirement makes the allocator spill catastrophically — R9's (384,6)
// cap of 80 == need 80 produced a 40-VGPR body + 452 MB scratch. Keep
// >= one granule (16) of slack.
// cfP/erP/adjb prefetch one full iteration ahead; V loads at body top
// (~500 cyc in-body lead). No online max (logits bounded, masked p == 0).
// ---------------------------------------------------------------------------
__global__ __launch_bounds__(320, 5) void attn(const unsigned* __restrict__ adjb,
                                               const float* __restrict__ e_l2,
                                               const float* __restrict__ cfT,
                                               const float* __restrict__ Wc2,
                                               const u32x4* __restrict__ cfP4,
                                               const u32x4* __restrict__ erP4,
                                               const bf16_t* __restrict__ hT2,
                                               float* __restrict__ out) {
  __shared__ float Obuf[16][64];
  __shared__ float Sbuf[16][2];
  const int tid = threadIdx.x;
  const int w = tid >> 6;        // 0..4
  const int lane = tid & 63;
  const int il = lane & 15;
  const int quad = lane >> 4;
  const int ibase = blockIdx.x * 16;
  const int hg = blockIdx.y;     // head pair: heads hg*2, hg*2+1
  const int i = ibase + il;

  for (int idx = tid; idx < 16 * 64; idx += 320) (&Obuf[0][0])[idx] = 0.f;
  if (tid < 32) (&Sbuf[0][0])[tid] = 0.f;
  __syncthreads();

  f32x2 cfi2[CF];
#pragma unroll
  for (int f = 0; f < CF; ++f) { float v = cfT[f * NN + i]; cfi2[f] = (f32x2){v, v}; }
  f32x2 el2[2];
  {
    f32x2 e0 = *(const f32x2*)&e_l2[i * HC + hg * 2];
#pragma unroll
    for (int u = 0; u < 2; ++u) el2[u] = (f32x2){e0[u], e0[u]};
  }
  float wc[2][CF];
#pragma unroll
  for (int h = 0; h < 2; ++h)
#pragma unroll
    for (int f = 0; f < CF; ++f) wc[h][f] = Wc2[(hg * 2 + h) * CF + f];

  f32x4 acc[2][2];
#pragma unroll
  for (int h = 0; h < 2; ++h)
#pragma unroll
    for (int d = 0; d < 2; ++d) acc[h][d] = (f32x4){0.f, 0.f, 0.f, 0.f};
  f32x2 S2[2];
#pragma unroll
  for (int h = 0; h < 2; ++h) S2[h] = (f32x2){0.f, 0.f};

  const bf16_t* hTbase = hT2 + (size_t)hg * 2 * ((NN / 32) * 1024) + quad * 256 + il * 8;
  const u32x4* cfb = cfP4 + quad * CF;           // c-stride 4*CF  (u32x4 units)
  const u32x4* erb = erP4 + quad * HC + hg * 2;  // c-stride 4*HC
  const unsigned* adjrow = adjb + i * 128;

  // ---- prime the prefetch registers for chunk c = w ----
  u32x4 cfc[CF];
#pragma unroll
  for (int f = 0; f < CF; ++f) cfc[f] = cfb[w * (4 * CF) + f];
  u32x4 erc[2];
#pragma unroll
  for (int h = 0; h < 2; ++h) erc[h] = erb[w * (4 * HC) + h];
  unsigned mc = adjrow[w];

  for (int c = w; c < NN / 32; c += 5) {
    // V fragments: issued at body top, consumed at the end (~500 cyc lead)
    const bf16_t* bp0 = hTbase + c * 1024;
    const bf16_t* bp1 = bp0 + (NN / 32) * 1024;
    bf16x8 b00 = *(const bf16x8*)bp0;
    bf16x8 b01 = *(const bf16x8*)(bp0 + 128);
    bf16x8 b10 = *(const bf16x8*)bp1;
    bf16x8 b11 = *(const bf16x8*)(bp1 + 128);

    // leaky(el + er) from prefetched erc (registers, no wait)
    f32x2 arg[2][4];
#pragma unroll
    for (int h = 0; h < 2; ++h)
#pragma unroll
      for (int p = 0; p < 4; ++p) {
        f32x2 s = el2[h] + unpk(erc[h][p]);
        arg[h][p] = __builtin_elementwise_max(s, 0.2f * s);
      }
    // curvature bias from prefetched cfc
#pragma unroll
    for (int f = 0; f < CF; ++f) {
#pragma unroll
      for (int p = 0; p < 4; ++p) {
        f32x2 d2 = cfi2[f] - unpk(cfc[f][p]);
        f32x2 ab = __builtin_elementwise_max(d2, -d2);
#pragma unroll
        for (int h = 0; h < 2; ++h) {
          f32x2 wsp = (f32x2){wc[h][f], wc[h][f]};
          arg[h][p] = __builtin_elementwise_fma(ab, wsp, arg[h][p]);
        }
      }
    }

    // ---- prefetch chunk c+5 (cur buffers dead; one full body of lead) ----
    const int cn = (c + 5) & (NN / 32 - 1);
    const unsigned m8 = (mc >> (quad * 8)) & 0xffu;
#pragma unroll
    for (int f = 0; f < CF; ++f) cfc[f] = cfb[cn * (4 * CF) + f];
#pragma unroll
    for (int h = 0; h < 2; ++h) erc[h] = erb[cn * (4 * HC) + h];
    mc = adjrow[cn];

    // mask bits -> float pairs
    f32x2 mf2[4];
#pragma unroll
    for (int p = 0; p < 4; ++p)
      mf2[p] = (f32x2){(float)((m8 >> (2 * p)) & 1u), (float)((m8 >> (2 * p + 1)) & 1u)};

#pragma unroll
    for (int h = 0; h < 2; ++h) {
      bf16x8 af;
#pragma unroll
      for (int p = 0; p < 4; ++p) {
        f32x2 pv = (f32x2){EXP2F(arg[h][p][0]), EXP2F(arg[h][p][1])};
        pv = pv * mf2[p];          // v_pk_mul
        S2[h] += pv;               // v_pk_add
        af[2 * p] = (bf16_t)pv[0];
        af[2 * p + 1] = (bf16_t)pv[1];
      }
      acc[h][0] = __builtin_amdgcn_mfma_f32_16x16x32_bf16(af, h ? b10 : b00, acc[h][0], 0, 0, 0);
      acc[h][1] = __builtin_amdgcn_mfma_f32_16x16x32_bf16(af, h ? b11 : b01, acc[h][1], 0, 0, 0);
    }
  }

  // reduce S across quads (lanes il, il+16, il+32, il+48)
#pragma unroll
  for (int h = 0; h < 2; ++h) {
    float v = S2[h][0] + S2[h][1];
    v += __shfl_xor(v, 16, 64);
    v += __shfl_xor(v, 32, 64);
    if (quad == 0) atomicAdd(&Sbuf[il][h], v);
  }
  // accumulate O partials: C/D layout row = quad*4+r (i), col = il (d half)
#pragma unroll
  for (int h = 0; h < 2; ++h)
#pragma unroll
    for (int dh = 0; dh < 2; ++dh)
#pragma unroll
      for (int r = 0; r < 4; ++r)
        atomicAdd(&Obuf[quad * 4 + r][h * DC + dh * 16 + il], acc[h][dh][r]);
  __syncthreads();

  // epilogue: divide by softmax denom, coalesced store
  for (int idx = tid; idx < 16 * 64; idx += 320) {
    int row = idx >> 6;
    int colg = idx & 63;
    out[(size_t)(ibase + row) * OC + hg * 64 + colg] =
        Obuf[row][colg] / Sbuf[row][colg >> 5];
  }
}

// ---------------------------------------------------------------------------
extern "C" void kernel_launch(void* const* d_in, const int* in_sizes, int n_in,
                              void* d_out, int out_size, void* d_ws, size_t ws_size,
                              hipStream_t stream) {
  const float* x    = (const float*)d_in[0];
  // d_in[1] = positions — unused by the reference
  const float* cfeat= (const float*)d_in[2];
  const int*   adj  = (const int*)d_in[3];
  const float* W    = (const float*)d_in[4];
  const float* a_l  = (const float*)d_in[5];
  const float* a_r  = (const float*)d_in[6];
  const float* Wc   = (const float*)d_in[7];
  const float* gate = (const float*)d_in[8];
  float* out = (float*)d_out;

  char* ws = (char*)d_ws;
  bf16_t*   hT2  = (bf16_t*)ws;                              // 2 MB
  unsigned* adjb = (unsigned*)(ws + (2u << 20));             // 2 MB
  float*    e_l2 = (float*)(ws + (4u << 20));                // 128 KB
  float*    cfT  = (float*)(ws + (4u << 20) + (128u << 10)); // 96 KB
  float*    Wc2  = (float*)(ws + (4u << 20) + (256u << 10)); // 192 B
  bf16_t*   cfP  = (bf16_t*)(ws + (4u << 20) + (320u << 10));// 48 KB
  bf16_t*   erP  = (bf16_t*)(ws + (4u << 20) + (384u << 10));// 64 KB

  prep_all<<<2560, 256, 0, stream>>>(x, W, a_l, a_r, adj, cfeat, Wc, gate,
                                     e_l2, erP, hT2, adjb, cfT, cfP, Wc2);
  attn<<<dim3(NN / 16, 4), 320, 0, stream>>>(adjb, e_l2, cfT, Wc2,
                                             (const u32x4*)cfP, (const u32x4*)erP,
                                             hT2, out);
}

// Round 11
// 277.399 us; speedup vs baseline: 1.3848x; 1.1468x over previous
//
#include <hip/hip_runtime.h>

#define NN 4096     // nodes
#define HC 8        // heads
#define DC 32       // dim per head
#define OC 256      // out channels = HC*DC
#define KC 256      // in channels
#define CF 6        // curvature features

typedef __bf16 bf16_t;
typedef bf16_t bf16x8 __attribute__((ext_vector_type(8)));
typedef float f32x4 __attribute__((ext_vector_type(4)));
typedef float f32x2 __attribute__((ext_vector_type(2)));
typedef unsigned u32x4 __attribute__((ext_vector_type(4)));

#if defined(__has_builtin)
#if __has_builtin(__builtin_amdgcn_exp2f)
#define EXP2F(x) __builtin_amdgcn_exp2f(x)
#else
#define EXP2F(x) exp2f(x)
#endif
#else
#define EXP2F(x) exp2f(x)
#endif

// bf16 pair (one dword: lo16 = t_even, hi16 = t_odd) -> f32x2 (bf16 is
// truncated f32: unpack = 1 shl + 1 and).
static __device__ __forceinline__ f32x2 unpk(unsigned dw) {
  union { unsigned u; float f; } lo, hi;
  lo.u = dw << 16;
  hi.u = dw & 0xffff0000u;
  return (f32x2){lo.f, hi.f};
}

// ---------------------------------------------------------------------------
// Kernel 1: heterogeneous prep.
// Blocks 0..511 (gemm role): h-GEMM (64 rows x 1 head) + e_l (f32) +
//   e_r packed bf16 in attn's lane order (erP[c][q][h][t8]) + V as bf16 in
//   attn's B-fragment order (hT2[head][c][q][d32][t8]).
// Blocks 512..2559 (pack role): ballot-pack adj -> 2MB bitmask; cfT (f32,
//   i-side) + cfP packed bf16 in attn's lane order (cfP[c][q][f][t8]); Wc2.
// ---------------------------------------------------------------------------
__global__ __launch_bounds__(256) void prep_all(const float* __restrict__ x,
                                                const float* __restrict__ W,
                                                const float* __restrict__ a_l,
                                                const float* __restrict__ a_r,
                                                const int* __restrict__ adj,
                                                const float* __restrict__ cfeat,
                                                const float* __restrict__ Wc,
                                                const float* __restrict__ gate,
                                                float* __restrict__ e_l2,
                                                bf16_t* __restrict__ erP,
                                                bf16_t* __restrict__ hT2,
                                                unsigned* __restrict__ adjb,
                                                float* __restrict__ cfT,
                                                bf16_t* __restrict__ cfP,
                                                float* __restrict__ Wc2) {
  __shared__ float As[16][68];   // [k][i]
  __shared__ float Bs[16][36];   // [k][c]
  __shared__ float Ct[DC][65];   // [c][i]
  const float LOG2E = 1.44269504088896340736f;
  const int t = threadIdx.x;
  const int bid = blockIdx.x;

  if (bid >= 512) {
    // ---------------- pack role ----------------
    const int pb = bid - 512;                    // 0..2047
    const int ptid = pb * 256 + t;
    const int lane = t & 63;
    const int wv = pb * 4 + (t >> 6);            // 0..8191
    for (int it = 0; it < 32; ++it) {
      int g = wv * 32 + it;                      // segment id
      int i = g >> 6;
      int s = g & 63;
      int v = adj[(size_t)i * NN + s * 64 + lane];
      unsigned long long m = __ballot(v > 0);
      if (lane == 0) *(unsigned long long*)(adjb + i * 128 + s * 2) = m;
    }
    if (ptid < NN * CF) {
      int j = ptid / CF, f = ptid - j * CF;
      float v = cfeat[ptid];
      cfT[f * NN + j] = v;
      int cc = j >> 5, qq = (j >> 3) & 3, tt = j & 7;
      cfP[((cc * 4 + qq) * CF + f) * 8 + tt] = (bf16_t)v;
    }
    if (ptid < HC * CF) Wc2[ptid] = Wc[ptid] * gate[0] * LOG2E;
    return;
  }

  // ---------------- gemm role ----------------
  const int i0 = (bid & 63) * 64;
  const int head = bid >> 6;
  const int c0 = head * DC;
  const int tx = t & 7;          // col group (4 cols)
  const int ty = t >> 3;         // row pair (2 rows)
  const int lr = t >> 2;         // staging row 0..63
  const int lk = (t & 3) * 4;    // staging k 0,4,8,12

  float acc[2][4] = {};
  for (int kk = 0; kk < KC; kk += 16) {
    f32x4 av = *(const f32x4*)&x[(size_t)(i0 + lr) * KC + kk + lk];
    f32x4 wv;
    if (t < 128) wv = *(const f32x4*)&W[(size_t)(c0 + (t >> 2)) * KC + kk + lk];
    __syncthreads();
    As[lk + 0][lr] = av[0]; As[lk + 1][lr] = av[1];
    As[lk + 2][lr] = av[2]; As[lk + 3][lr] = av[3];
    if (t < 128) {
      int br = t >> 2;
      Bs[lk + 0][br] = wv[0]; Bs[lk + 1][br] = wv[1];
      Bs[lk + 2][br] = wv[2]; Bs[lk + 3][br] = wv[3];
    }
    __syncthreads();
#pragma unroll
    for (int k = 0; k < 16; ++k) {
      f32x2 a = *(const f32x2*)&As[k][ty * 2];
      f32x4 b = *(const f32x4*)&Bs[k][tx * 4];
#pragma unroll
      for (int r = 0; r < 2; ++r)
#pragma unroll
        for (int u = 0; u < 4; ++u)
          acc[r][u] += a[r] * b[u];
    }
  }

  // e_l (f32) / e_r (packed bf16, attn lane order), reduce across 8 tx lanes
  f32x4 al4 = *(const f32x4*)&a_l[c0 + tx * 4];
  f32x4 ar4 = *(const f32x4*)&a_r[c0 + tx * 4];
#pragma unroll
  for (int r = 0; r < 2; ++r) {
    float el = acc[r][0] * al4[0] + acc[r][1] * al4[1] +
               acc[r][2] * al4[2] + acc[r][3] * al4[3];
    float er = acc[r][0] * ar4[0] + acc[r][1] * ar4[1] +
               acc[r][2] * ar4[2] + acc[r][3] * ar4[3];
    el += __shfl_xor(el, 1, 64); el += __shfl_xor(el, 2, 64); el += __shfl_xor(el, 4, 64);
    er += __shfl_xor(er, 1, 64); er += __shfl_xor(er, 2, 64); er += __shfl_xor(er, 4, 64);
    if (tx == 0) {
      int j = i0 + ty * 2 + r;
      e_l2[j * HC + head] = el * LOG2E;
      int cc = j >> 5, qq = (j >> 3) & 3, tt = j & 7;
      erP[((cc * 4 + qq) * HC + head) * 8 + tt] = (bf16_t)(er * LOG2E);
    }
  }

  // transpose to B-fragment layout via LDS
#pragma unroll
  for (int r = 0; r < 2; ++r)
#pragma unroll
    for (int u = 0; u < 4; ++u)
      Ct[tx * 4 + u][ty * 2 + r] = acc[r][u];
  __syncthreads();
  const size_t base = (size_t)head * (NN / 32) * 1024 + (size_t)(bid & 63) * 2048;
#pragma unroll
  for (int rep = 0; rep < 8; ++rep) {
    int idx = rep * 256 + t;                 // enumerates [chunkL][q][d][t8]
    int dd = (idx >> 3) & 31;
    int jl = (idx >> 10) * 32 + ((idx >> 8) & 3) * 8 + (idx & 7);
    hT2[base + idx] = (bf16_t)Ct[dd][jl];
  }
}

// ---------------------------------------------------------------------------
// Kernel 2: fused masked attention, 2 heads/block, register-prefetched.
// Grid (NN/16, 4) = 1024 blocks x 384 threads (6 waves), lb(384,4).
// KEY (R9/R10 lesson): min_waves > 4 makes the allocator spill this body
// (R9 cap 80 == need 80 -> 452 MB scratch; R10 cap 96 > need 80 STILL
// spilled). Only cap 128 (min_waves=4) reliably compiles to 64 VGPR +
// 16 AGPR = 80 combined. R8's occupancy (16 waves/CU) was GRID-limited,
// not register-limited: at 80 regs HW fits 6 waves/SIMD. So: keep the
// safe cap and raise waves/block instead — 4 blocks/CU x 6 waves =
// 24 waves/CU, all 1024 blocks co-resident (1536 thr <= 2048,
// 6 x 80 = 480 <= 512 regs/SIMD, LDS 4 x 4.6 KB).
// cfP/erP/adjb prefetch one full iteration ahead; V loads at body top
// (~500 cyc in-body lead). No online max (logits bounded, masked p == 0).
// ---------------------------------------------------------------------------
__global__ __launch_bounds__(384, 4) void attn(const unsigned* __restrict__ adjb,
                                               const float* __restrict__ e_l2,
                                               const float* __restrict__ cfT,
                                               const float* __restrict__ Wc2,
                                               const u32x4* __restrict__ cfP4,
                                               const u32x4* __restrict__ erP4,
                                               const bf16_t* __restrict__ hT2,
                                               float* __restrict__ out) {
  __shared__ float Obuf[16][64];
  __shared__ float Sbuf[16][2];
  const int tid = threadIdx.x;
  const int w = tid >> 6;        // 0..5
  const int lane = tid & 63;
  const int il = lane & 15;
  const int quad = lane >> 4;
  const int ibase = blockIdx.x * 16;
  const int hg = blockIdx.y;     // head pair: heads hg*2, hg*2+1
  const int i = ibase + il;

  for (int idx = tid; idx < 16 * 64; idx += 384) (&Obuf[0][0])[idx] = 0.f;
  if (tid < 32) (&Sbuf[0][0])[tid] = 0.f;
  __syncthreads();

  f32x2 cfi2[CF];
#pragma unroll
  for (int f = 0; f < CF; ++f) { float v = cfT[f * NN + i]; cfi2[f] = (f32x2){v, v}; }
  f32x2 el2[2];
  {
    f32x2 e0 = *(const f32x2*)&e_l2[i * HC + hg * 2];
#pragma unroll
    for (int u = 0; u < 2; ++u) el2[u] = (f32x2){e0[u], e0[u]};
  }
  float wc[2][CF];
#pragma unroll
  for (int h = 0; h < 2; ++h)
#pragma unroll
    for (int f = 0; f < CF; ++f) wc[h][f] = Wc2[(hg * 2 + h) * CF + f];

  f32x4 acc[2][2];
#pragma unroll
  for (int h = 0; h < 2; ++h)
#pragma unroll
    for (int d = 0; d < 2; ++d) acc[h][d] = (f32x4){0.f, 0.f, 0.f, 0.f};
  f32x2 S2[2];
#pragma unroll
  for (int h = 0; h < 2; ++h) S2[h] = (f32x2){0.f, 0.f};

  const bf16_t* hTbase = hT2 + (size_t)hg * 2 * ((NN / 32) * 1024) + quad * 256 + il * 8;
  const u32x4* cfb = cfP4 + quad * CF;           // c-stride 4*CF  (u32x4 units)
  const u32x4* erb = erP4 + quad * HC + hg * 2;  // c-stride 4*HC
  const unsigned* adjrow = adjb + i * 128;

  // ---- prime the prefetch registers for chunk c = w ----
  u32x4 cfc[CF];
#pragma unroll
  for (int f = 0; f < CF; ++f) cfc[f] = cfb[w * (4 * CF) + f];
  u32x4 erc[2];
#pragma unroll
  for (int h = 0; h < 2; ++h) erc[h] = erb[w * (4 * HC) + h];
  unsigned mc = adjrow[w];

  for (int c = w; c < NN / 32; c += 6) {
    // V fragments: issued at body top, consumed at the end (~500 cyc lead)
    const bf16_t* bp0 = hTbase + c * 1024;
    const bf16_t* bp1 = bp0 + (NN / 32) * 1024;
    bf16x8 b00 = *(const bf16x8*)bp0;
    bf16x8 b01 = *(const bf16x8*)(bp0 + 128);
    bf16x8 b10 = *(const bf16x8*)bp1;
    bf16x8 b11 = *(const bf16x8*)(bp1 + 128);

    // leaky(el + er) from prefetched erc (registers, no wait)
    f32x2 arg[2][4];
#pragma unroll
    for (int h = 0; h < 2; ++h)
#pragma unroll
      for (int p = 0; p < 4; ++p) {
        f32x2 s = el2[h] + unpk(erc[h][p]);
        arg[h][p] = __builtin_elementwise_max(s, 0.2f * s);
      }
    // curvature bias from prefetched cfc
#pragma unroll
    for (int f = 0; f < CF; ++f) {
#pragma unroll
      for (int p = 0; p < 4; ++p) {
        f32x2 d2 = cfi2[f] - unpk(cfc[f][p]);
        f32x2 ab = __builtin_elementwise_max(d2, -d2);
#pragma unroll
        for (int h = 0; h < 2; ++h) {
          f32x2 wsp = (f32x2){wc[h][f], wc[h][f]};
          arg[h][p] = __builtin_elementwise_fma(ab, wsp, arg[h][p]);
        }
      }
    }

    // ---- prefetch chunk c+6 (cur buffers dead; one full body of lead) ----
    const int cn = (c + 6) & (NN / 32 - 1);
    const unsigned m8 = (mc >> (quad * 8)) & 0xffu;
#pragma unroll
    for (int f = 0; f < CF; ++f) cfc[f] = cfb[cn * (4 * CF) + f];
#pragma unroll
    for (int h = 0; h < 2; ++h) erc[h] = erb[cn * (4 * HC) + h];
    mc = adjrow[cn];

    // mask bits -> float pairs
    f32x2 mf2[4];
#pragma unroll
    for (int p = 0; p < 4; ++p)
      mf2[p] = (f32x2){(float)((m8 >> (2 * p)) & 1u), (float)((m8 >> (2 * p + 1)) & 1u)};

#pragma unroll
    for (int h = 0; h < 2; ++h) {
      bf16x8 af;
#pragma unroll
      for (int p = 0; p < 4; ++p) {
        f32x2 pv = (f32x2){EXP2F(arg[h][p][0]), EXP2F(arg[h][p][1])};
        pv = pv * mf2[p];          // v_pk_mul
        S2[h] += pv;               // v_pk_add
        af[2 * p] = (bf16_t)pv[0];
        af[2 * p + 1] = (bf16_t)pv[1];
      }
      acc[h][0] = __builtin_amdgcn_mfma_f32_16x16x32_bf16(af, h ? b10 : b00, acc[h][0], 0, 0, 0);
      acc[h][1] = __builtin_amdgcn_mfma_f32_16x16x32_bf16(af, h ? b11 : b01, acc[h][1], 0, 0, 0);
    }
  }

  // reduce S across quads (lanes il, il+16, il+32, il+48)
#pragma unroll
  for (int h = 0; h < 2; ++h) {
    float v = S2[h][0] + S2[h][1];
    v += __shfl_xor(v, 16, 64);
    v += __shfl_xor(v, 32, 64);
    if (quad == 0) atomicAdd(&Sbuf[il][h], v);
  }
  // accumulate O partials: C/D layout row = quad*4+r (i), col = il (d half)
#pragma unroll
  for (int h = 0; h < 2; ++h)
#pragma unroll
    for (int dh = 0; dh < 2; ++dh)
#pragma unroll
      for (int r = 0; r < 4; ++r)
        atomicAdd(&Obuf[quad * 4 + r][h * DC + dh * 16 + il], acc[h][dh][r]);
  __syncthreads();

  // epilogue: divide by softmax denom, coalesced store
  for (int idx = tid; idx < 16 * 64; idx += 384) {
    int row = idx >> 6;
    int colg = idx & 63;
    out[(size_t)(ibase + row) * OC + hg * 64 + colg] =
        Obuf[row][colg] / Sbuf[row][colg >> 5];
  }
}

// ---------------------------------------------------------------------------
extern "C" void kernel_launch(void* const* d_in, const int* in_sizes, int n_in,
                              void* d_out, int out_size, void* d_ws, size_t ws_size,
                              hipStream_t stream) {
  const float* x    = (const float*)d_in[0];
  // d_in[1] = positions — unused by the reference
  const float* cfeat= (const float*)d_in[2];
  const int*   adj  = (const int*)d_in[3];
  const float* W    = (const float*)d_in[4];
  const float* a_l  = (const float*)d_in[5];
  const float* a_r  = (const float*)d_in[6];
  const float* Wc   = (const float*)d_in[7];
  const float* gate = (const float*)d_in[8];
  float* out = (float*)d_out;

  char* ws = (char*)d_ws;
  bf16_t*   hT2  = (bf16_t*)ws;                              // 2 MB
  unsigned* adjb = (unsigned*)(ws + (2u << 20));             // 2 MB
  float*    e_l2 = (float*)(ws + (4u << 20));                // 128 KB
  float*    cfT  = (float*)(ws + (4u << 20) + (128u << 10)); // 96 KB
  float*    Wc2  = (float*)(ws + (4u << 20) + (256u << 10)); // 192 B
  bf16_t*   cfP  = (bf16_t*)(ws + (4u << 20) + (320u << 10));// 48 KB
  bf16_t*   erP  = (bf16_t*)(ws + (4u << 20) + (384u << 10));// 64 KB

  prep_all<<<2560, 256, 0, stream>>>(x, W, a_l, a_r, adj, cfeat, Wc, gate,
                                     e_l2, erP, hT2, adjb, cfT, cfP, Wc2);
  attn<<<dim3(NN / 16, 4), 384, 0, stream>>>(adjb, e_l2, cfT, Wc2,
                                             (const u32x4*)cfP, (const u32x4*)erP,
                                             hT2, out);
}

// Round 12
// 227.972 us; speedup vs baseline: 1.6851x; 1.2168x over previous
//
#include <hip/hip_runtime.h>

#define NN 4096     // nodes
#define HC 8        // heads
#define DC 32       // dim per head
#define OC 256      // out channels = HC*DC
#define KC 256      // in channels
#define CF 6        // curvature features

typedef __bf16 bf16_t;
typedef bf16_t bf16x8 __attribute__((ext_vector_type(8)));
typedef float f32x4 __attribute__((ext_vector_type(4)));
typedef float f32x2 __attribute__((ext_vector_type(2)));
typedef unsigned u32x4 __attribute__((ext_vector_type(4)));

#define AS1 __attribute__((address_space(1)))
#define AS3 __attribute__((address_space(3)))

#if defined(__has_builtin)
#if __has_builtin(__builtin_amdgcn_exp2f)
#define EXP2F(x) __builtin_amdgcn_exp2f(x)
#else
#define EXP2F(x) exp2f(x)
#endif
#else
#define EXP2F(x) exp2f(x)
#endif

// bf16 pair (one dword: lo16 = t_even, hi16 = t_odd) -> f32x2 (bf16 is
// truncated f32: unpack = 1 shl + 1 and).
static __device__ __forceinline__ f32x2 unpk(unsigned dw) {
  union { unsigned u; float f; } lo, hi;
  lo.u = dw << 16;
  hi.u = dw & 0xffff0000u;
  return (f32x2){lo.f, hi.f};
}

// ---------------------------------------------------------------------------
// Kernel 1: heterogeneous prep (unchanged from R8).
// Blocks 0..511 (gemm role): h-GEMM (64 rows x 1 head) + e_l (f32) +
//   e_r packed bf16 in attn's lane order (erP[c][q][h][t8]) + V as bf16 in
//   attn's B-fragment order (hT2[head][c][q][d32][t8]).
// Blocks 512..2559 (pack role): ballot-pack adj -> 2MB bitmask; cfT (f32,
//   i-side) + cfP packed bf16 in attn's lane order (cfP[c][q][f][t8]); Wc2.
// ---------------------------------------------------------------------------
__global__ __launch_bounds__(256) void prep_all(const float* __restrict__ x,
                                                const float* __restrict__ W,
                                                const float* __restrict__ a_l,
                                                const float* __restrict__ a_r,
                                                const int* __restrict__ adj,
                                                const float* __restrict__ cfeat,
                                                const float* __restrict__ Wc,
                                                const float* __restrict__ gate,
                                                float* __restrict__ e_l2,
                                                bf16_t* __restrict__ erP,
                                                bf16_t* __restrict__ hT2,
                                                unsigned* __restrict__ adjb,
                                                float* __restrict__ cfT,
                                                bf16_t* __restrict__ cfP,
                                                float* __restrict__ Wc2) {
  __shared__ float As[16][68];   // [k][i]
  __shared__ float Bs[16][36];   // [k][c]
  __shared__ float Ct[DC][65];   // [c][i]
  const float LOG2E = 1.44269504088896340736f;
  const int t = threadIdx.x;
  const int bid = blockIdx.x;

  if (bid >= 512) {
    // ---------------- pack role ----------------
    const int pb = bid - 512;                    // 0..2047
    const int ptid = pb * 256 + t;
    const int lane = t & 63;
    const int wv = pb * 4 + (t >> 6);            // 0..8191
    for (int it = 0; it < 32; ++it) {
      int g = wv * 32 + it;                      // segment id
      int i = g >> 6;
      int s = g & 63;
      int v = adj[(size_t)i * NN + s * 64 + lane];
      unsigned long long m = __ballot(v > 0);
      if (lane == 0) *(unsigned long long*)(adjb + i * 128 + s * 2) = m;
    }
    if (ptid < NN * CF) {
      int j = ptid / CF, f = ptid - j * CF;
      float v = cfeat[ptid];
      cfT[f * NN + j] = v;
      int cc = j >> 5, qq = (j >> 3) & 3, tt = j & 7;
      cfP[((cc * 4 + qq) * CF + f) * 8 + tt] = (bf16_t)v;
    }
    if (ptid < HC * CF) Wc2[ptid] = Wc[ptid] * gate[0] * LOG2E;
    return;
  }

  // ---------------- gemm role ----------------
  const int i0 = (bid & 63) * 64;
  const int head = bid >> 6;
  const int c0 = head * DC;
  const int tx = t & 7;          // col group (4 cols)
  const int ty = t >> 3;         // row pair (2 rows)
  const int lr = t >> 2;         // staging row 0..63
  const int lk = (t & 3) * 4;    // staging k 0,4,8,12

  float acc[2][4] = {};
  for (int kk = 0; kk < KC; kk += 16) {
    f32x4 av = *(const f32x4*)&x[(size_t)(i0 + lr) * KC + kk + lk];
    f32x4 wv;
    if (t < 128) wv = *(const f32x4*)&W[(size_t)(c0 + (t >> 2)) * KC + kk + lk];
    __syncthreads();
    As[lk + 0][lr] = av[0]; As[lk + 1][lr] = av[1];
    As[lk + 2][lr] = av[2]; As[lk + 3][lr] = av[3];
    if (t < 128) {
      int br = t >> 2;
      Bs[lk + 0][br] = wv[0]; Bs[lk + 1][br] = wv[1];
      Bs[lk + 2][br] = wv[2]; Bs[lk + 3][br] = wv[3];
    }
    __syncthreads();
#pragma unroll
    for (int k = 0; k < 16; ++k) {
      f32x2 a = *(const f32x2*)&As[k][ty * 2];
      f32x4 b = *(const f32x4*)&Bs[k][tx * 4];
#pragma unroll
      for (int r = 0; r < 2; ++r)
#pragma unroll
        for (int u = 0; u < 4; ++u)
          acc[r][u] += a[r] * b[u];
    }
  }

  // e_l (f32) / e_r (packed bf16, attn lane order), reduce across 8 tx lanes
  f32x4 al4 = *(const f32x4*)&a_l[c0 + tx * 4];
  f32x4 ar4 = *(const f32x4*)&a_r[c0 + tx * 4];
#pragma unroll
  for (int r = 0; r < 2; ++r) {
    float el = acc[r][0] * al4[0] + acc[r][1] * al4[1] +
               acc[r][2] * al4[2] + acc[r][3] * al4[3];
    float er = acc[r][0] * ar4[0] + acc[r][1] * ar4[1] +
               acc[r][2] * ar4[2] + acc[r][3] * ar4[3];
    el += __shfl_xor(el, 1, 64); el += __shfl_xor(el, 2, 64); el += __shfl_xor(el, 4, 64);
    er += __shfl_xor(er, 1, 64); er += __shfl_xor(er, 2, 64); er += __shfl_xor(er, 4, 64);
    if (tx == 0) {
      int j = i0 + ty * 2 + r;
      e_l2[j * HC + head] = el * LOG2E;
      int cc = j >> 5, qq = (j >> 3) & 3, tt = j & 7;
      erP[((cc * 4 + qq) * HC + head) * 8 + tt] = (bf16_t)(er * LOG2E);
    }
  }

  // transpose to B-fragment layout via LDS
#pragma unroll
  for (int r = 0; r < 2; ++r)
#pragma unroll
    for (int u = 0; u < 4; ++u)
      Ct[tx * 4 + u][ty * 2 + r] = acc[r][u];
  __syncthreads();
  const size_t base = (size_t)head * (NN / 32) * 1024 + (size_t)(bid & 63) * 2048;
#pragma unroll
  for (int rep = 0; rep < 8; ++rep) {
    int idx = rep * 256 + t;                 // enumerates [chunkL][q][d][t8]
    int dd = (idx >> 3) & 31;
    int jl = (idx >> 10) * 32 + ((idx >> 8) & 3) * 8 + (idx & 7);
    hT2[base + idx] = (bf16_t)Ct[dd][jl];
  }
}

// ---------------------------------------------------------------------------
// Kernel 2: fused masked attention, 2 heads/block, fully prefetched.
// Geometry = R8 exactly (the measured optimum: 1024 blocks x 256 thr,
// lb(256,4), 16 waves/CU; R9/R10 tighter caps spilled, R11 6-wave blocks
// broke dispatcher packing). New in R12: V fragments prefetched one full
// iteration ahead via __builtin_amdgcn_global_load_lds into a per-wave
// 2x4KB LDS double-buffer — async DMA holds NO VGPRs (R7's register
// version spilled). Source addresses are per-lane (legal; only the LDS
// dest is lane*16-strided, which round-trips identically via ds_read).
// cfP/erP/adjb register prefetch unchanged. Even a conservative vmcnt(0)
// before the ds_reads only waits on one-body-old (~1300 cyc) ops.
// No online max (logits bounded, masked p == 0 exactly).
// ---------------------------------------------------------------------------
__global__ __launch_bounds__(256, 4) void attn(const unsigned* __restrict__ adjb,
                                               const float* __restrict__ e_l2,
                                               const float* __restrict__ cfT,
                                               const float* __restrict__ Wc2,
                                               const u32x4* __restrict__ cfP4,
                                               const u32x4* __restrict__ erP4,
                                               const bf16_t* __restrict__ hT2,
                                               float* __restrict__ out) {
  __shared__ float Obuf[16][64];
  __shared__ float Sbuf[16][2];
  __shared__ __align__(16) char vbuf[4][2][4096];   // [wave][parity][4 frags x 1KB]
  const int tid = threadIdx.x;
  const int w = tid >> 6;        // 0..3
  const int lane = tid & 63;
  const int il = lane & 15;
  const int quad = lane >> 4;
  const int ibase = blockIdx.x * 16;
  const int hg = blockIdx.y;     // head pair: heads hg*2, hg*2+1
  const int i = ibase + il;

  for (int idx = tid; idx < 16 * 64; idx += 256) (&Obuf[0][0])[idx] = 0.f;
  if (tid < 32) (&Sbuf[0][0])[tid] = 0.f;
  __syncthreads();

  f32x2 cfi2[CF];
#pragma unroll
  for (int f = 0; f < CF; ++f) { float v = cfT[f * NN + i]; cfi2[f] = (f32x2){v, v}; }
  f32x2 el2[2];
  {
    f32x2 e0 = *(const f32x2*)&e_l2[i * HC + hg * 2];
#pragma unroll
    for (int u = 0; u < 2; ++u) el2[u] = (f32x2){e0[u], e0[u]};
  }
  float wc[2][CF];
#pragma unroll
  for (int h = 0; h < 2; ++h)
#pragma unroll
    for (int f = 0; f < CF; ++f) wc[h][f] = Wc2[(hg * 2 + h) * CF + f];

  f32x4 acc[2][2];
#pragma unroll
  for (int h = 0; h < 2; ++h)
#pragma unroll
    for (int d = 0; d < 2; ++d) acc[h][d] = (f32x4){0.f, 0.f, 0.f, 0.f};
  f32x2 S2[2];
#pragma unroll
  for (int h = 0; h < 2; ++h) S2[h] = (f32x2){0.f, 0.f};

  const bf16_t* hTbase = hT2 + (size_t)hg * 2 * ((NN / 32) * 1024) + quad * 256 + il * 8;
  const u32x4* cfb = cfP4 + quad * CF;           // c-stride 4*CF  (u32x4 units)
  const u32x4* erb = erP4 + quad * HC + hg * 2;  // c-stride 4*HC
  const unsigned* adjrow = adjb + i * 128;

  // ---- prime V DMA for chunk c = w into parity 0 (async, no VGPRs held) ----
  {
    const bf16_t* p0 = hTbase + w * 1024;
    const bf16_t* p1 = p0 + (NN / 32) * 1024;
    char* lb = &vbuf[w][0][0];
    __builtin_amdgcn_global_load_lds((const AS1 void*)p0,         (AS3 void*)(lb),        16, 0, 0);
    __builtin_amdgcn_global_load_lds((const AS1 void*)(p0 + 128), (AS3 void*)(lb + 1024), 16, 0, 0);
    __builtin_amdgcn_global_load_lds((const AS1 void*)p1,         (AS3 void*)(lb + 2048), 16, 0, 0);
    __builtin_amdgcn_global_load_lds((const AS1 void*)(p1 + 128), (AS3 void*)(lb + 3072), 16, 0, 0);
  }
  // ---- prime the scalar-stream prefetch registers for chunk c = w ----
  u32x4 cfc[CF];
#pragma unroll
  for (int f = 0; f < CF; ++f) cfc[f] = cfb[w * (4 * CF) + f];
  u32x4 erc[2];
#pragma unroll
  for (int h = 0; h < 2; ++h) erc[h] = erb[w * (4 * HC) + h];
  unsigned mc = adjrow[w];

  int par = 0;
  for (int c = w; c < NN / 32; c += 4) {
    // V fragments for chunk c from LDS (DMA'd one full iteration ago)
    const char* lbr = &vbuf[w][par][0];
    bf16x8 b00 = *(const bf16x8*)(lbr + lane * 16);
    bf16x8 b01 = *(const bf16x8*)(lbr + 1024 + lane * 16);
    bf16x8 b10 = *(const bf16x8*)(lbr + 2048 + lane * 16);
    bf16x8 b11 = *(const bf16x8*)(lbr + 3072 + lane * 16);

    // leaky(el + er) from prefetched erc (registers, no wait)
    f32x2 arg[2][4];
#pragma unroll
    for (int h = 0; h < 2; ++h)
#pragma unroll
      for (int p = 0; p < 4; ++p) {
        f32x2 s = el2[h] + unpk(erc[h][p]);
        arg[h][p] = __builtin_elementwise_max(s, 0.2f * s);
      }
    // curvature bias from prefetched cfc
#pragma unroll
    for (int f = 0; f < CF; ++f) {
#pragma unroll
      for (int p = 0; p < 4; ++p) {
        f32x2 d2 = cfi2[f] - unpk(cfc[f][p]);
        f32x2 ab = __builtin_elementwise_max(d2, -d2);
#pragma unroll
        for (int h = 0; h < 2; ++h) {
          f32x2 wsp = (f32x2){wc[h][f], wc[h][f]};
          arg[h][p] = __builtin_elementwise_fma(ab, wsp, arg[h][p]);
        }
      }
    }

    // ---- prefetch chunk c+4 (one full body of lead) ----
    const int cn = (c + 4) & (NN / 32 - 1);
    const unsigned m8 = (mc >> (quad * 8)) & 0xffu;
    {
      const bf16_t* p0 = hTbase + cn * 1024;
      const bf16_t* p1 = p0 + (NN / 32) * 1024;
      char* lb = &vbuf[w][par ^ 1][0];
      __builtin_amdgcn_global_load_lds((const AS1 void*)p0,         (AS3 void*)(lb),        16, 0, 0);
      __builtin_amdgcn_global_load_lds((const AS1 void*)(p0 + 128), (AS3 void*)(lb + 1024), 16, 0, 0);
      __builtin_amdgcn_global_load_lds((const AS1 void*)p1,         (AS3 void*)(lb + 2048), 16, 0, 0);
      __builtin_amdgcn_global_load_lds((const AS1 void*)(p1 + 128), (AS3 void*)(lb + 3072), 16, 0, 0);
    }
#pragma unroll
    for (int f = 0; f < CF; ++f) cfc[f] = cfb[cn * (4 * CF) + f];
#pragma unroll
    for (int h = 0; h < 2; ++h) erc[h] = erb[cn * (4 * HC) + h];
    mc = adjrow[cn];

    // mask bits -> float pairs
    f32x2 mf2[4];
#pragma unroll
    for (int p = 0; p < 4; ++p)
      mf2[p] = (f32x2){(float)((m8 >> (2 * p)) & 1u), (float)((m8 >> (2 * p + 1)) & 1u)};

#pragma unroll
    for (int h = 0; h < 2; ++h) {
      bf16x8 af;
#pragma unroll
      for (int p = 0; p < 4; ++p) {
        f32x2 pv = (f32x2){EXP2F(arg[h][p][0]), EXP2F(arg[h][p][1])};
        pv = pv * mf2[p];          // v_pk_mul
        S2[h] += pv;               // v_pk_add
        af[2 * p] = (bf16_t)pv[0];
        af[2 * p + 1] = (bf16_t)pv[1];
      }
      acc[h][0] = __builtin_amdgcn_mfma_f32_16x16x32_bf16(af, h ? b10 : b00, acc[h][0], 0, 0, 0);
      acc[h][1] = __builtin_amdgcn_mfma_f32_16x16x32_bf16(af, h ? b11 : b01, acc[h][1], 0, 0, 0);
    }
    par ^= 1;
  }

  // reduce S across quads (lanes il, il+16, il+32, il+48)
#pragma unroll
  for (int h = 0; h < 2; ++h) {
    float v = S2[h][0] + S2[h][1];
    v += __shfl_xor(v, 16, 64);
    v += __shfl_xor(v, 32, 64);
    if (quad == 0) atomicAdd(&Sbuf[il][h], v);
  }
  // accumulate O partials: C/D layout row = quad*4+r (i), col = il (d half)
#pragma unroll
  for (int h = 0; h < 2; ++h)
#pragma unroll
    for (int dh = 0; dh < 2; ++dh)
#pragma unroll
      for (int r = 0; r < 4; ++r)
        atomicAdd(&Obuf[quad * 4 + r][h * DC + dh * 16 + il], acc[h][dh][r]);
  __syncthreads();

  // epilogue: divide by softmax denom, coalesced store
  for (int idx = tid; idx < 16 * 64; idx += 256) {
    int row = idx >> 6;
    int colg = idx & 63;
    out[(size_t)(ibase + row) * OC + hg * 64 + colg] =
        Obuf[row][colg] / Sbuf[row][colg >> 5];
  }
}

// ---------------------------------------------------------------------------
extern "C" void kernel_launch(void* const* d_in, const int* in_sizes, int n_in,
                              void* d_out, int out_size, void* d_ws, size_t ws_size,
                              hipStream_t stream) {
  const float* x    = (const float*)d_in[0];
  // d_in[1] = positions — unused by the reference
  const float* cfeat= (const float*)d_in[2];
  const int*   adj  = (const int*)d_in[3];
  const float* W    = (const float*)d_in[4];
  const float* a_l  = (const float*)d_in[5];
  const float* a_r  = (const float*)d_in[6];
  const float* Wc   = (const float*)d_in[7];
  const float* gate = (const float*)d_in[8];
  float* out = (float*)d_out;

  char* ws = (char*)d_ws;
  bf16_t*   hT2  = (bf16_t*)ws;                              // 2 MB
  unsigned* adjb = (unsigned*)(ws + (2u << 20));             // 2 MB
  float*    e_l2 = (float*)(ws + (4u << 20));                // 128 KB
  float*    cfT  = (float*)(ws + (4u << 20) + (128u << 10)); // 96 KB
  float*    Wc2  = (float*)(ws + (4u << 20) + (256u << 10)); // 192 B
  bf16_t*   cfP  = (bf16_t*)(ws + (4u << 20) + (320u << 10));// 48 KB
  bf16_t*   erP  = (bf16_t*)(ws + (4u << 20) + (384u << 10));// 64 KB

  prep_all<<<2560, 256, 0, stream>>>(x, W, a_l, a_r, adj, cfeat, Wc, gate,
                                     e_l2, erP, hT2, adjb, cfT, cfP, Wc2);
  attn<<<dim3(NN / 16, 4), 256, 0, stream>>>(adjb, e_l2, cfT, Wc2,
                                             (const u32x4*)cfP, (const u32x4*)erP,
                                             hT2, out);
}

// Round 13
// 227.058 us; speedup vs baseline: 1.6919x; 1.0040x over previous
//
#include <hip/hip_runtime.h>

#define NN 4096     // nodes
#define HC 8        // heads
#define DC 32       // dim per head
#define OC 256      // out channels = HC*DC
#define KC 256      // in channels
#define CF 6        // curvature features

typedef __bf16 bf16_t;
typedef bf16_t bf16x8 __attribute__((ext_vector_type(8)));
typedef float f32x4 __attribute__((ext_vector_type(4)));
typedef float f32x2 __attribute__((ext_vector_type(2)));
typedef unsigned u32x4 __attribute__((ext_vector_type(4)));

#if defined(__has_builtin)
#if __has_builtin(__builtin_amdgcn_exp2f)
#define EXP2F(x) __builtin_amdgcn_exp2f(x)
#else
#define EXP2F(x) exp2f(x)
#endif
#else
#define EXP2F(x) exp2f(x)
#endif

// bf16 pair (one dword: lo16 = t_even, hi16 = t_odd) -> f32x2 (bf16 is
// truncated f32: unpack = 1 shl + 1 and).
static __device__ __forceinline__ f32x2 unpk(unsigned dw) {
  union { unsigned u; float f; } lo, hi;
  lo.u = dw << 16;
  hi.u = dw & 0xffff0000u;
  return (f32x2){lo.f, hi.f};
}

// ---------------------------------------------------------------------------
// Kernel 1: heterogeneous prep (unchanged since R8).
// Blocks 0..511 (gemm role): h-GEMM (64 rows x 1 head) + e_l (f32) +
//   e_r packed bf16 in attn's lane order (erP[c][q][h][t8]) + V as bf16 in
//   attn's B-fragment order (hT2[head][c][q][d32][t8]).
// Blocks 512..2559 (pack role): ballot-pack adj -> 2MB bitmask; cfT (f32,
//   i-side) + cfP packed bf16 in attn's lane order (cfP[c][q][f][t8]); Wc2.
// ---------------------------------------------------------------------------
__global__ __launch_bounds__(256) void prep_all(const float* __restrict__ x,
                                                const float* __restrict__ W,
                                                const float* __restrict__ a_l,
                                                const float* __restrict__ a_r,
                                                const int* __restrict__ adj,
                                                const float* __restrict__ cfeat,
                                                const float* __restrict__ Wc,
                                                const float* __restrict__ gate,
                                                float* __restrict__ e_l2,
                                                bf16_t* __restrict__ erP,
                                                bf16_t* __restrict__ hT2,
                                                unsigned* __restrict__ adjb,
                                                float* __restrict__ cfT,
                                                bf16_t* __restrict__ cfP,
                                                float* __restrict__ Wc2) {
  __shared__ float As[16][68];   // [k][i]
  __shared__ float Bs[16][36];   // [k][c]
  __shared__ float Ct[DC][65];   // [c][i]
  const float LOG2E = 1.44269504088896340736f;
  const int t = threadIdx.x;
  const int bid = blockIdx.x;

  if (bid >= 512) {
    // ---------------- pack role ----------------
    const int pb = bid - 512;                    // 0..2047
    const int ptid = pb * 256 + t;
    const int lane = t & 63;
    const int wv = pb * 4 + (t >> 6);            // 0..8191
    for (int it = 0; it < 32; ++it) {
      int g = wv * 32 + it;                      // segment id
      int i = g >> 6;
      int s = g & 63;
      int v = adj[(size_t)i * NN + s * 64 + lane];
      unsigned long long m = __ballot(v > 0);
      if (lane == 0) *(unsigned long long*)(adjb + i * 128 + s * 2) = m;
    }
    if (ptid < NN * CF) {
      int j = ptid / CF, f = ptid - j * CF;
      float v = cfeat[ptid];
      cfT[f * NN + j] = v;
      int cc = j >> 5, qq = (j >> 3) & 3, tt = j & 7;
      cfP[((cc * 4 + qq) * CF + f) * 8 + tt] = (bf16_t)v;
    }
    if (ptid < HC * CF) Wc2[ptid] = Wc[ptid] * gate[0] * LOG2E;
    return;
  }

  // ---------------- gemm role ----------------
  const int i0 = (bid & 63) * 64;
  const int head = bid >> 6;
  const int c0 = head * DC;
  const int tx = t & 7;          // col group (4 cols)
  const int ty = t >> 3;         // row pair (2 rows)
  const int lr = t >> 2;         // staging row 0..63
  const int lk = (t & 3) * 4;    // staging k 0,4,8,12

  float acc[2][4] = {};
  for (int kk = 0; kk < KC; kk += 16) {
    f32x4 av = *(const f32x4*)&x[(size_t)(i0 + lr) * KC + kk + lk];
    f32x4 wv;
    if (t < 128) wv = *(const f32x4*)&W[(size_t)(c0 + (t >> 2)) * KC + kk + lk];
    __syncthreads();
    As[lk + 0][lr] = av[0]; As[lk + 1][lr] = av[1];
    As[lk + 2][lr] = av[2]; As[lk + 3][lr] = av[3];
    if (t < 128) {
      int br = t >> 2;
      Bs[lk + 0][br] = wv[0]; Bs[lk + 1][br] = wv[1];
      Bs[lk + 2][br] = wv[2]; Bs[lk + 3][br] = wv[3];
    }
    __syncthreads();
#pragma unroll
    for (int k = 0; k < 16; ++k) {
      f32x2 a = *(const f32x2*)&As[k][ty * 2];
      f32x4 b = *(const f32x4*)&Bs[k][tx * 4];
#pragma unroll
      for (int r = 0; r < 2; ++r)
#pragma unroll
        for (int u = 0; u < 4; ++u)
          acc[r][u] += a[r] * b[u];
    }
  }

  // e_l (f32) / e_r (packed bf16, attn lane order), reduce across 8 tx lanes
  f32x4 al4 = *(const f32x4*)&a_l[c0 + tx * 4];
  f32x4 ar4 = *(const f32x4*)&a_r[c0 + tx * 4];
#pragma unroll
  for (int r = 0; r < 2; ++r) {
    float el = acc[r][0] * al4[0] + acc[r][1] * al4[1] +
               acc[r][2] * al4[2] + acc[r][3] * al4[3];
    float er = acc[r][0] * ar4[0] + acc[r][1] * ar4[1] +
               acc[r][2] * ar4[2] + acc[r][3] * ar4[3];
    el += __shfl_xor(el, 1, 64); el += __shfl_xor(el, 2, 64); el += __shfl_xor(el, 4, 64);
    er += __shfl_xor(er, 1, 64); er += __shfl_xor(er, 2, 64); er += __shfl_xor(er, 4, 64);
    if (tx == 0) {
      int j = i0 + ty * 2 + r;
      e_l2[j * HC + head] = el * LOG2E;
      int cc = j >> 5, qq = (j >> 3) & 3, tt = j & 7;
      erP[((cc * 4 + qq) * HC + head) * 8 + tt] = (bf16_t)(er * LOG2E);
    }
  }

  // transpose to B-fragment layout via LDS
#pragma unroll
  for (int r = 0; r < 2; ++r)
#pragma unroll
    for (int u = 0; u < 4; ++u)
      Ct[tx * 4 + u][ty * 2 + r] = acc[r][u];
  __syncthreads();
  const size_t base = (size_t)head * (NN / 32) * 1024 + (size_t)(bid & 63) * 2048;
#pragma unroll
  for (int rep = 0; rep < 8; ++rep) {
    int idx = rep * 256 + t;                 // enumerates [chunkL][q][d][t8]
    int dd = (idx >> 3) & 31;
    int jl = (idx >> 10) * 32 + ((idx >> 8) & 3) * 8 + (idx & 7);
    hT2[base + idx] = (bf16_t)Ct[dd][jl];
  }
}

// ---------------------------------------------------------------------------
// Kernel 2: fused masked attention, 2 heads/block, register-prefetched.
// Geometry = R8 (measured optimum: 1024 blocks x 256 thr, lb(256,4),
// 16 waves/CU; tighter caps spill [R9/R10], 6-wave blocks break dispatcher
// packing [R11], LDS-DMA V neutral [R12], occupancy 30-51% shows no perf
// correlation -> issue-bound). New in R13: chunk loop unrolled x2
// (trip = 32, exactly divisible) to amortize per-iteration loop control /
// address arithmetic / prefetch-pointer overhead and give the scheduler a
// 2-body window to interleave loads with VALU. R8 measured 80/128 regs;
// 48 regs of slack absorb the unroll's longer live ranges.
// cfP/erP/adjb prefetch one iteration ahead; V loads at body top.
// No online max (logits bounded, masked p == 0 exactly).
// ---------------------------------------------------------------------------
__global__ __launch_bounds__(256, 4) void attn(const unsigned* __restrict__ adjb,
                                               const float* __restrict__ e_l2,
                                               const float* __restrict__ cfT,
                                               const float* __restrict__ Wc2,
                                               const u32x4* __restrict__ cfP4,
                                               const u32x4* __restrict__ erP4,
                                               const bf16_t* __restrict__ hT2,
                                               float* __restrict__ out) {
  __shared__ float Obuf[16][64];
  __shared__ float Sbuf[16][2];
  const int tid = threadIdx.x;
  const int w = tid >> 6;        // 0..3
  const int lane = tid & 63;
  const int il = lane & 15;
  const int quad = lane >> 4;
  const int ibase = blockIdx.x * 16;
  const int hg = blockIdx.y;     // head pair: heads hg*2, hg*2+1
  const int i = ibase + il;

  for (int idx = tid; idx < 16 * 64; idx += 256) (&Obuf[0][0])[idx] = 0.f;
  if (tid < 32) (&Sbuf[0][0])[tid] = 0.f;
  __syncthreads();

  f32x2 cfi2[CF];
#pragma unroll
  for (int f = 0; f < CF; ++f) { float v = cfT[f * NN + i]; cfi2[f] = (f32x2){v, v}; }
  f32x2 el2[2];
  {
    f32x2 e0 = *(const f32x2*)&e_l2[i * HC + hg * 2];
#pragma unroll
    for (int u = 0; u < 2; ++u) el2[u] = (f32x2){e0[u], e0[u]};
  }
  float wc[2][CF];
#pragma unroll
  for (int h = 0; h < 2; ++h)
#pragma unroll
    for (int f = 0; f < CF; ++f) wc[h][f] = Wc2[(hg * 2 + h) * CF + f];

  f32x4 acc[2][2];
#pragma unroll
  for (int h = 0; h < 2; ++h)
#pragma unroll
    for (int d = 0; d < 2; ++d) acc[h][d] = (f32x4){0.f, 0.f, 0.f, 0.f};
  f32x2 S2[2];
#pragma unroll
  for (int h = 0; h < 2; ++h) S2[h] = (f32x2){0.f, 0.f};

  const bf16_t* hTbase = hT2 + (size_t)hg * 2 * ((NN / 32) * 1024) + quad * 256 + il * 8;
  const u32x4* cfb = cfP4 + quad * CF;           // c-stride 4*CF  (u32x4 units)
  const u32x4* erb = erP4 + quad * HC + hg * 2;  // c-stride 4*HC
  const unsigned* adjrow = adjb + i * 128;

  // ---- prime the prefetch registers for chunk c = w ----
  u32x4 cfc[CF];
#pragma unroll
  for (int f = 0; f < CF; ++f) cfc[f] = cfb[w * (4 * CF) + f];
  u32x4 erc[2];
#pragma unroll
  for (int h = 0; h < 2; ++h) erc[h] = erb[w * (4 * HC) + h];
  unsigned mc = adjrow[w];

#pragma unroll 2
  for (int c = w; c < NN / 32; c += 4) {
    // V fragments: issued at body top, consumed at the end (~500 cyc lead)
    const bf16_t* bp0 = hTbase + c * 1024;
    const bf16_t* bp1 = bp0 + (NN / 32) * 1024;
    bf16x8 b00 = *(const bf16x8*)bp0;
    bf16x8 b01 = *(const bf16x8*)(bp0 + 128);
    bf16x8 b10 = *(const bf16x8*)bp1;
    bf16x8 b11 = *(const bf16x8*)(bp1 + 128);

    // leaky(el + er) from prefetched erc (registers, no wait)
    f32x2 arg[2][4];
#pragma unroll
    for (int h = 0; h < 2; ++h)
#pragma unroll
      for (int p = 0; p < 4; ++p) {
        f32x2 s = el2[h] + unpk(erc[h][p]);
        arg[h][p] = __builtin_elementwise_max(s, 0.2f * s);
      }
    // curvature bias from prefetched cfc
#pragma unroll
    for (int f = 0; f < CF; ++f) {
#pragma unroll
      for (int p = 0; p < 4; ++p) {
        f32x2 d2 = cfi2[f] - unpk(cfc[f][p]);
        f32x2 ab = __builtin_elementwise_max(d2, -d2);
#pragma unroll
        for (int h = 0; h < 2; ++h) {
          f32x2 wsp = (f32x2){wc[h][f], wc[h][f]};
          arg[h][p] = __builtin_elementwise_fma(ab, wsp, arg[h][p]);
        }
      }
    }

    // ---- prefetch chunk c+4 (cur buffers dead; one full body of lead) ----
    const int cn = (c + 4) & (NN / 32 - 1);
    const unsigned m8 = (mc >> (quad * 8)) & 0xffu;
#pragma unroll
    for (int f = 0; f < CF; ++f) cfc[f] = cfb[cn * (4 * CF) + f];
#pragma unroll
    for (int h = 0; h < 2; ++h) erc[h] = erb[cn * (4 * HC) + h];
    mc = adjrow[cn];

    // mask bits -> float pairs
    f32x2 mf2[4];
#pragma unroll
    for (int p = 0; p < 4; ++p)
      mf2[p] = (f32x2){(float)((m8 >> (2 * p)) & 1u), (float)((m8 >> (2 * p + 1)) & 1u)};

#pragma unroll
    for (int h = 0; h < 2; ++h) {
      bf16x8 af;
#pragma unroll
      for (int p = 0; p < 4; ++p) {
        f32x2 pv = (f32x2){EXP2F(arg[h][p][0]), EXP2F(arg[h][p][1])};
        pv = pv * mf2[p];          // v_pk_mul
        S2[h] += pv;               // v_pk_add
        af[2 * p] = (bf16_t)pv[0];
        af[2 * p + 1] = (bf16_t)pv[1];
      }
      acc[h][0] = __builtin_amdgcn_mfma_f32_16x16x32_bf16(af, h ? b10 : b00, acc[h][0], 0, 0, 0);
      acc[h][1] = __builtin_amdgcn_mfma_f32_16x16x32_bf16(af, h ? b11 : b01, acc[h][1], 0, 0, 0);
    }
  }

  // reduce S across quads (lanes il, il+16, il+32, il+48)
#pragma unroll
  for (int h = 0; h < 2; ++h) {
    float v = S2[h][0] + S2[h][1];
    v += __shfl_xor(v, 16, 64);
    v += __shfl_xor(v, 32, 64);
    if (quad == 0) atomicAdd(&Sbuf[il][h], v);
  }
  // accumulate O partials: C/D layout row = quad*4+r (i), col = il (d half)
#pragma unroll
  for (int h = 0; h < 2; ++h)
#pragma unroll
    for (int dh = 0; dh < 2; ++dh)
#pragma unroll
      for (int r = 0; r < 4; ++r)
        atomicAdd(&Obuf[quad * 4 + r][h * DC + dh * 16 + il], acc[h][dh][r]);
  __syncthreads();

  // epilogue: divide by softmax denom, coalesced store
  for (int idx = tid; idx < 16 * 64; idx += 256) {
    int row = idx >> 6;
    int colg = idx & 63;
    out[(size_t)(ibase + row) * OC + hg * 64 + colg] =
        Obuf[row][colg] / Sbuf[row][colg >> 5];
  }
}

// ---------------------------------------------------------------------------
extern "C" void kernel_launch(void* const* d_in, const int* in_sizes, int n_in,
                              void* d_out, int out_size, void* d_ws, size_t ws_size,
                              hipStream_t stream) {
  const float* x    = (const float*)d_in[0];
  // d_in[1] = positions — unused by the reference
  const float* cfeat= (const float*)d_in[2];
  const int*   adj  = (const int*)d_in[3];
  const float* W    = (const float*)d_in[4];
  const float* a_l  = (const float*)d_in[5];
  const float* a_r  = (const float*)d_in[6];
  const float* Wc   = (const float*)d_in[7];
  const float* gate = (const float*)d_in[8];
  float* out = (float*)d_out;

  char* ws = (char*)d_ws;
  bf16_t*   hT2  = (bf16_t*)ws;                              // 2 MB
  unsigned* adjb = (unsigned*)(ws + (2u << 20));             // 2 MB
  float*    e_l2 = (float*)(ws + (4u << 20));                // 128 KB
  float*    cfT  = (float*)(ws + (4u << 20) + (128u << 10)); // 96 KB
  float*    Wc2  = (float*)(ws + (4u << 20) + (256u << 10)); // 192 B
  bf16_t*   cfP  = (bf16_t*)(ws + (4u << 20) + (320u << 10));// 48 KB
  bf16_t*   erP  = (bf16_t*)(ws + (4u << 20) + (384u << 10));// 64 KB

  prep_all<<<2560, 256, 0, stream>>>(x, W, a_l, a_r, adj, cfeat, Wc, gate,
                                     e_l2, erP, hT2, adjb, cfT, cfP, Wc2);
  attn<<<dim3(NN / 16, 4), 256, 0, stream>>>(adjb, e_l2, cfT, Wc2,
                                             (const u32x4*)cfP, (const u32x4*)erP,
                                             hT2, out);
}